// Round 1
// baseline (281.903 us; speedup 1.0000x reference)
//
#include <hip/hip_runtime.h>

typedef __bf16 bf16x8 __attribute__((ext_vector_type(8)));
typedef __bf16 bf16x4 __attribute__((ext_vector_type(4)));
typedef float  f32x4  __attribute__((ext_vector_type(4)));

#define BM 128
#define BN 64
#define BK 64

// NT GEMM: C[i][j] = sum_k A[i*lda+k] * B[j*ldb+k]  (+ epilogue)
// EPI: 0 = +bias, bf16 row-major store
//      1 = +bias, bf16 TRANSPOSED store into (B,256,1024)  [v projection]
//      2 = exp, bf16 row-major store                        [logits -> E]
//      3 = plain fp32 row-major store                       [PV -> out]
template<int EPI>
__global__ __launch_bounds__(256)
void gemm_nt(const __bf16* __restrict__ A, const __bf16* __restrict__ B,
             void* __restrict__ Cv, const float* __restrict__ bias,
             int lda, int ldb, int ldc, int K,
             long sA, long sB, long sC)
{
    __shared__ __bf16 As[BM][BK + 8];   // +8 bf16 pad -> 2-way LDS conflicts only (free)
    __shared__ __bf16 Bs[BN][BK + 8];

    const int tid  = threadIdx.x;
    const int wave = tid >> 6;
    const int lane = tid & 63;
    const int quad = lane >> 4;
    const int l16  = lane & 15;

    const int m0 = blockIdx.x * BM;
    const int n0 = blockIdx.y * BN;
    const int z  = blockIdx.z;

    const __bf16* Ab = A + (size_t)z * sA;
    const __bf16* Bb = B + (size_t)z * sB;

    f32x4 acc[2][4] = {};

    const int arow = tid >> 1, aseg = tid & 1;   // A staging: 2 threads/row, 32 bf16 each
    const int brow = tid >> 2, bseg = tid & 3;   // B staging: 4 threads/row, 16 bf16 each

    for (int k0 = 0; k0 < K; k0 += BK) {
        __syncthreads();
        {
            const uint4* s4 = (const uint4*)(Ab + (size_t)(m0 + arow) * lda + k0 + aseg * 32);
            uint4* d4 = (uint4*)&As[arow][aseg * 32];
            d4[0] = s4[0]; d4[1] = s4[1]; d4[2] = s4[2]; d4[3] = s4[3];
        }
        {
            const uint4* s4 = (const uint4*)(Bb + (size_t)(n0 + brow) * ldb + k0 + bseg * 16);
            uint4* d4 = (uint4*)&Bs[brow][bseg * 16];
            d4[0] = s4[0]; d4[1] = s4[1];
        }
        __syncthreads();

        #pragma unroll
        for (int kk = 0; kk < BK; kk += 32) {
            bf16x8 a0 = *(const bf16x8*)&As[wave * 32 +  0 + l16][kk + quad * 8];
            bf16x8 a1 = *(const bf16x8*)&As[wave * 32 + 16 + l16][kk + quad * 8];
            #pragma unroll
            for (int nt = 0; nt < 4; nt++) {
                bf16x8 b = *(const bf16x8*)&Bs[nt * 16 + l16][kk + quad * 8];
                acc[0][nt] = __builtin_amdgcn_mfma_f32_16x16x32_bf16(a0, b, acc[0][nt], 0, 0, 0);
                acc[1][nt] = __builtin_amdgcn_mfma_f32_16x16x32_bf16(a1, b, acc[1][nt], 0, 0, 0);
            }
        }
    }

    // Epilogue. C/D layout (verified m89/m91): row = quad*4 + reg, col = l16.
    const int mbase = m0 + wave * 32 + quad * 4;
    #pragma unroll
    for (int mt = 0; mt < 2; mt++) {
        #pragma unroll
        for (int nt = 0; nt < 4; nt++) {
            const int n = n0 + nt * 16 + l16;
            if constexpr (EPI == 0) {
                __bf16* C = (__bf16*)Cv + (size_t)z * sC;
                const float bn = bias[n];
                #pragma unroll
                for (int r = 0; r < 4; r++) {
                    const int m = mbase + mt * 16 + r;
                    C[(size_t)m * ldc + n] = (__bf16)(acc[mt][nt][r] + bn);
                }
            } else if constexpr (EPI == 1) {
                // v transposed: vT[b][d=n][mloc] with N-per-batch = 1024
                __bf16* C = (__bf16*)Cv;
                const float bn = bias[n];
                const int m = mbase + mt * 16;          // aligned to 4, same batch for r=0..3
                const int bidx = m >> 10, mloc = m & 1023;
                bf16x4 pack;
                #pragma unroll
                for (int r = 0; r < 4; r++) pack[r] = (__bf16)(acc[mt][nt][r] + bn);
                *(bf16x4*)(C + (size_t)bidx * 262144 + (size_t)n * 1024 + mloc) = pack;
            } else if constexpr (EPI == 2) {
                __bf16* C = (__bf16*)Cv + (size_t)z * sC;
                #pragma unroll
                for (int r = 0; r < 4; r++) {
                    const int m = mbase + mt * 16 + r;
                    C[(size_t)m * ldc + n] = (__bf16)__expf(acc[mt][nt][r]);
                }
            } else {
                float* C = (float*)Cv + (size_t)z * sC;
                #pragma unroll
                for (int r = 0; r < 4; r++) {
                    const int m = mbase + mt * 16 + r;
                    C[(size_t)m * ldc + n] = acc[mt][nt][r];
                }
            }
        }
    }
}

__global__ __launch_bounds__(256)
void cvt_f32_bf16(const float* __restrict__ src, __bf16* __restrict__ dst, int n8)
{
    const int i = blockIdx.x * 256 + threadIdx.x;
    if (i >= n8) return;
    const float4* s = (const float4*)src;
    const float4 f0 = s[i * 2], f1 = s[i * 2 + 1];
    bf16x8 o;
    o[0] = (__bf16)f0.x; o[1] = (__bf16)f0.y; o[2] = (__bf16)f0.z; o[3] = (__bf16)f0.w;
    o[4] = (__bf16)f1.x; o[5] = (__bf16)f1.y; o[6] = (__bf16)f1.z; o[7] = (__bf16)f1.w;
    ((bf16x8*)dst)[i] = o;
}

// Softmax over batch axis: S[n,m] = sum_b E[b,n,m]; E <- E / S (in place).
// One thread owns 8 consecutive m positions across all 32 batch slices.
__global__ __launch_bounds__(256)
void softmax_norm(__bf16* __restrict__ E)
{
    const size_t p = (size_t)blockIdx.x * 256 + threadIdx.x;  // bf16x8 index in one slice
    bf16x8* E8 = (bf16x8*)E;
    float s[8] = {0.f, 0.f, 0.f, 0.f, 0.f, 0.f, 0.f, 0.f};
    #pragma unroll
    for (int b = 0; b < 32; b++) {
        bf16x8 e = E8[(size_t)b * 131072 + p];
        #pragma unroll
        for (int j = 0; j < 8; j++) s[j] += (float)e[j];
    }
    float rs[8];
    #pragma unroll
    for (int j = 0; j < 8; j++) rs[j] = 1.0f / s[j];
    #pragma unroll
    for (int b = 0; b < 32; b++) {
        bf16x8 e = E8[(size_t)b * 131072 + p];
        #pragma unroll
        for (int j = 0; j < 8; j++) e[j] = (__bf16)((float)e[j] * rs[j]);
        E8[(size_t)b * 131072 + p] = e;
    }
}

extern "C" void kernel_launch(void* const* d_in, const int* in_sizes, int n_in,
                              void* d_out, int out_size, void* d_ws, size_t ws_size,
                              hipStream_t stream)
{
    const float* x  = (const float*)d_in[0];
    const float* Wq = (const float*)d_in[1];
    const float* bq = (const float*)d_in[2];
    const float* Wk = (const float*)d_in[3];
    const float* bk = (const float*)d_in[4];
    const float* Wv = (const float*)d_in[5];
    const float* bv = (const float*)d_in[6];
    float* out = (float*)d_out;

    // Workspace layout (bytes):
    //   [0,16M)    xb   bf16 (32768 x 256)
    //   [16M,32M)  qb   bf16
    //   [32M,48M)  kb   bf16
    //   [48M,64M)  vT   bf16 (32 x 256 x 1024)
    //   [64M,128M) E    bf16 (32 x 1024 x 1024)
    //   [128M,..)  Wqb/Wkb/Wvb bf16 (128 KB each)
    char* ws = (char*)d_ws;
    __bf16* xb  = (__bf16*)(ws);
    __bf16* qb  = (__bf16*)(ws + (16u << 20));
    __bf16* kb  = (__bf16*)(ws + (32u << 20));
    __bf16* vT  = (__bf16*)(ws + (48u << 20));
    __bf16* E   = (__bf16*)(ws + (64u << 20));
    __bf16* Wqb = (__bf16*)(ws + (128u << 20));
    __bf16* Wkb = (__bf16*)(ws + (128u << 20) + (1u << 18));
    __bf16* Wvb = (__bf16*)(ws + (128u << 20) + (2u << 18));

    // 1) fp32 -> bf16 converts
    cvt_f32_bf16<<<4096, 256, 0, stream>>>(x,  xb,  1048576);
    cvt_f32_bf16<<<32,   256, 0, stream>>>(Wq, Wqb, 8192);
    cvt_f32_bf16<<<32,   256, 0, stream>>>(Wk, Wkb, 8192);
    cvt_f32_bf16<<<32,   256, 0, stream>>>(Wv, Wvb, 8192);

    // 2) projections: M=32768, N=256, K=256 (W row-major (O,D) => NT layout)
    gemm_nt<0><<<dim3(256, 4, 1), 256, 0, stream>>>(xb, Wqb, qb, bq, 256, 256, 256, 256, 0, 0, 0);
    gemm_nt<0><<<dim3(256, 4, 1), 256, 0, stream>>>(xb, Wkb, kb, bk, 256, 256, 256, 256, 0, 0, 0);
    gemm_nt<1><<<dim3(256, 4, 1), 256, 0, stream>>>(xb, Wvb, vT, bv, 256, 256, 0,   256, 0, 0, 0);

    // 3) E[b] = exp(q[b] @ k[b]^T): per-batch M=N=1024, K=256
    gemm_nt<2><<<dim3(8, 16, 32), 256, 0, stream>>>(qb, kb, E, nullptr, 256, 256, 1024, 256,
                                                    262144, 262144, 1048576);

    // 4) batch-axis softmax normalize (in place)
    softmax_norm<<<512, 256, 0, stream>>>(E);

    // 5) out[b] = attn[b] @ vT[b]^T: per-batch M=1024, N=256, K=1024, fp32 out
    gemm_nt<3><<<dim3(8, 4, 32), 256, 0, stream>>>(E, vT, out, nullptr, 1024, 1024, 256, 1024,
                                                   1048576, 262144, 262144);
}

// Round 2
// 227.743 us; speedup vs baseline: 1.2378x; 1.2378x over previous
//
#include <hip/hip_runtime.h>

typedef __bf16 bf16x8 __attribute__((ext_vector_type(8)));
typedef __bf16 bf16x4 __attribute__((ext_vector_type(4)));
typedef float  f32x4  __attribute__((ext_vector_type(4)));

#define BM 128
#define BN 128
#define BK 64

__device__ __forceinline__ void g2l16(const void* g, void* l) {
    __builtin_amdgcn_global_load_lds((const __attribute__((address_space(1))) void*)g,
                                     (__attribute__((address_space(3))) void*)l, 16, 0, 0);
}

// NT GEMM: C[i][j] = sum_k A[i*lda+k] * B[j*ldb+k]  (+ epilogue)
// 128x128 tile, BK=64, 4 waves in 2x2, each wave computes 64x64.
// LDS layout: unpadded [128][64] bf16 with XOR-swizzled 16B units:
//   physical_unit = logical_unit ^ (row & 7)  (8 units of 16B per row)
// Swizzle is applied at the global SOURCE column during global_load_lds
// staging (dest must be wave-uniform-base + lane*16B, so dest is fixed)
// and at the LDS fragment-read address. Fragment reads then spread a
// quad's 16 lanes across all 8 bank groups (2-way max = free, m136).
// EPI: 0 = +bias, bf16 row-major store
//      1 = +bias, bf16 TRANSPOSED store into (B,256,1024)  [v projection]
//      2 = exp, bf16 row-major store                        [logits -> E]
//      3 = plain fp32 row-major store                       [PV -> out]
template<int EPI>
__global__ __launch_bounds__(256)
void gemm_nt(const __bf16* __restrict__ A, const __bf16* __restrict__ B,
             void* __restrict__ Cv, const float* __restrict__ bias,
             int lda, int ldb, int ldc, int K,
             long sA, long sB, long sC)
{
    __shared__ __align__(16) __bf16 As[BM * BK];
    __shared__ __align__(16) __bf16 Bs[BN * BK];

    const int tid  = threadIdx.x;
    const int w    = tid >> 6;
    const int lane = tid & 63;
    const int quad = lane >> 4;
    const int l16  = lane & 15;
    const int wm   = w & 1;        // wave's 64-row block
    const int wn   = w >> 1;       // wave's 64-col block

    const int m0 = blockIdx.x * BM;
    const int n0 = blockIdx.y * BN;
    const int z  = blockIdx.z;

    const __bf16* Ab = A + (size_t)z * sA;
    const __bf16* Bb = B + (size_t)z * sB;

    // Staging geometry: chunk c covers rows [c*32, c*32+32), thread handles
    // row = c*32 + w*8 + lane/8, swizzled source col = ((lane&7)^(lane>>3))*8.
    const int srow = (w << 3) + (lane >> 3);
    const int scol = ((lane & 7) ^ (lane >> 3)) << 3;
    char* ldsA = (char*)As + (size_t)w * 1024;   // + c*4096; lane*16 added by HW
    char* ldsB = (char*)Bs + (size_t)w * 1024;

    const __bf16* Ag = Ab + (size_t)(m0 + srow) * lda + scol;
    const __bf16* Bg = Bb + (size_t)(n0 + srow) * ldb + scol;

    f32x4 acc[4][4] = {};

    for (int k0 = 0; k0 < K; k0 += BK) {
        __syncthreads();
        #pragma unroll
        for (int c = 0; c < 4; c++)
            g2l16(Ag + (size_t)(c * 32) * lda + k0, ldsA + c * 4096);
        #pragma unroll
        for (int c = 0; c < 4; c++)
            g2l16(Bg + (size_t)(c * 32) * ldb + k0, ldsB + c * 4096);
        __syncthreads();   // compiler drains vmcnt here

        #pragma unroll
        for (int kk = 0; kk < BK; kk += 32) {
            const int ub = kk >> 3;          // logical unit base: 0 or 4
            bf16x8 a[4], b[4];
            #pragma unroll
            for (int mt = 0; mt < 4; mt++) {
                const int row = wm * 64 + mt * 16 + l16;
                const int cp  = ((quad + ub) ^ (row & 7)) << 3;
                a[mt] = *(const bf16x8*)&As[row * BK + cp];
            }
            #pragma unroll
            for (int nt = 0; nt < 4; nt++) {
                const int row = wn * 64 + nt * 16 + l16;
                const int cp  = ((quad + ub) ^ (row & 7)) << 3;
                b[nt] = *(const bf16x8*)&Bs[row * BK + cp];
            }
            #pragma unroll
            for (int mt = 0; mt < 4; mt++)
                #pragma unroll
                for (int nt = 0; nt < 4; nt++)
                    acc[mt][nt] = __builtin_amdgcn_mfma_f32_16x16x32_bf16(
                        a[mt], b[nt], acc[mt][nt], 0, 0, 0);
        }
    }

    // Epilogue. C/D layout (verified m89/m91): row = quad*4 + reg, col = l16.
    #pragma unroll
    for (int mt = 0; mt < 4; mt++) {
        const int mb = m0 + wm * 64 + mt * 16 + quad * 4;
        #pragma unroll
        for (int nt = 0; nt < 4; nt++) {
            const int n = n0 + wn * 64 + nt * 16 + l16;
            if constexpr (EPI == 0) {
                __bf16* C = (__bf16*)Cv + (size_t)z * sC;
                const float bn = bias[n];
                #pragma unroll
                for (int r = 0; r < 4; r++)
                    C[(size_t)(mb + r) * ldc + n] = (__bf16)(acc[mt][nt][r] + bn);
            } else if constexpr (EPI == 1) {
                // v transposed: vT[b][d=n][mloc], batch stride 256*1024
                __bf16* C = (__bf16*)Cv;
                const float bn = bias[n];
                const int bidx = mb >> 10, mloc = mb & 1023;  // mb multiple of 4
                bf16x4 pack;
                #pragma unroll
                for (int r = 0; r < 4; r++) pack[r] = (__bf16)(acc[mt][nt][r] + bn);
                *(bf16x4*)(C + (size_t)bidx * 262144 + (size_t)n * 1024 + mloc) = pack;
            } else if constexpr (EPI == 2) {
                __bf16* C = (__bf16*)Cv + (size_t)z * sC;
                #pragma unroll
                for (int r = 0; r < 4; r++)
                    C[(size_t)(mb + r) * ldc + n] = (__bf16)__expf(acc[mt][nt][r]);
            } else {
                float* C = (float*)Cv + (size_t)z * sC;
                #pragma unroll
                for (int r = 0; r < 4; r++)
                    C[(size_t)(mb + r) * ldc + n] = acc[mt][nt][r];
            }
        }
    }
}

__global__ __launch_bounds__(256)
void cvt_f32_bf16(const float* __restrict__ src, __bf16* __restrict__ dst, int n8)
{
    const int i = blockIdx.x * 256 + threadIdx.x;
    if (i >= n8) return;
    const float4* s = (const float4*)src;
    const float4 f0 = s[i * 2], f1 = s[i * 2 + 1];
    bf16x8 o;
    o[0] = (__bf16)f0.x; o[1] = (__bf16)f0.y; o[2] = (__bf16)f0.z; o[3] = (__bf16)f0.w;
    o[4] = (__bf16)f1.x; o[5] = (__bf16)f1.y; o[6] = (__bf16)f1.z; o[7] = (__bf16)f1.w;
    ((bf16x8*)dst)[i] = o;
}

// Softmax over batch axis: S[n,m] = sum_b E[b,n,m]; E <- E / S (in place).
__global__ __launch_bounds__(256)
void softmax_norm(__bf16* __restrict__ E)
{
    const size_t p = (size_t)blockIdx.x * 256 + threadIdx.x;  // bf16x8 index in one slice
    bf16x8* E8 = (bf16x8*)E;
    float s[8] = {0.f, 0.f, 0.f, 0.f, 0.f, 0.f, 0.f, 0.f};
    #pragma unroll
    for (int b = 0; b < 32; b++) {
        bf16x8 e = E8[(size_t)b * 131072 + p];
        #pragma unroll
        for (int j = 0; j < 8; j++) s[j] += (float)e[j];
    }
    float rs[8];
    #pragma unroll
    for (int j = 0; j < 8; j++) rs[j] = 1.0f / s[j];
    #pragma unroll
    for (int b = 0; b < 32; b++) {
        bf16x8 e = E8[(size_t)b * 131072 + p];
        #pragma unroll
        for (int j = 0; j < 8; j++) e[j] = (__bf16)((float)e[j] * rs[j]);
        E8[(size_t)b * 131072 + p] = e;
    }
}

extern "C" void kernel_launch(void* const* d_in, const int* in_sizes, int n_in,
                              void* d_out, int out_size, void* d_ws, size_t ws_size,
                              hipStream_t stream)
{
    const float* x  = (const float*)d_in[0];
    const float* Wq = (const float*)d_in[1];
    const float* bq = (const float*)d_in[2];
    const float* Wk = (const float*)d_in[3];
    const float* bk = (const float*)d_in[4];
    const float* Wv = (const float*)d_in[5];
    const float* bv = (const float*)d_in[6];
    float* out = (float*)d_out;

    // Workspace layout (bytes):
    //   [0,16M)    xb   bf16 (32768 x 256)
    //   [16M,32M)  qb   bf16
    //   [32M,48M)  kb   bf16
    //   [48M,64M)  vT   bf16 (32 x 256 x 1024)
    //   [64M,128M) E    bf16 (32 x 1024 x 1024)
    //   [128M,..)  Wqb/Wkb/Wvb bf16 (128 KB each)
    char* ws = (char*)d_ws;
    __bf16* xb  = (__bf16*)(ws);
    __bf16* qb  = (__bf16*)(ws + (16u << 20));
    __bf16* kb  = (__bf16*)(ws + (32u << 20));
    __bf16* vT  = (__bf16*)(ws + (48u << 20));
    __bf16* E   = (__bf16*)(ws + (64u << 20));
    __bf16* Wqb = (__bf16*)(ws + (128u << 20));
    __bf16* Wkb = (__bf16*)(ws + (128u << 20) + (1u << 18));
    __bf16* Wvb = (__bf16*)(ws + (128u << 20) + (2u << 18));

    // 1) fp32 -> bf16 converts
    cvt_f32_bf16<<<4096, 256, 0, stream>>>(x,  xb,  1048576);
    cvt_f32_bf16<<<32,   256, 0, stream>>>(Wq, Wqb, 8192);
    cvt_f32_bf16<<<32,   256, 0, stream>>>(Wk, Wkb, 8192);
    cvt_f32_bf16<<<32,   256, 0, stream>>>(Wv, Wvb, 8192);

    // 2) projections: M=32768, N=256, K=256 (W row-major (O,D) => NT layout)
    gemm_nt<0><<<dim3(256, 2, 1), 256, 0, stream>>>(xb, Wqb, qb, bq, 256, 256, 256, 256, 0, 0, 0);
    gemm_nt<0><<<dim3(256, 2, 1), 256, 0, stream>>>(xb, Wkb, kb, bk, 256, 256, 256, 256, 0, 0, 0);
    gemm_nt<1><<<dim3(256, 2, 1), 256, 0, stream>>>(xb, Wvb, vT, bv, 256, 256, 0,   256, 0, 0, 0);

    // 3) E[b] = exp(q[b] @ k[b]^T): per-batch M=N=1024, K=256
    gemm_nt<2><<<dim3(8, 8, 32), 256, 0, stream>>>(qb, kb, E, nullptr, 256, 256, 1024, 256,
                                                   262144, 262144, 1048576);

    // 4) batch-axis softmax normalize (in place)
    softmax_norm<<<512, 256, 0, stream>>>(E);

    // 5) out[b] = attn[b] @ vT[b]^T: per-batch M=1024, N=256, K=1024, fp32 out
    gemm_nt<3><<<dim3(8, 2, 32), 256, 0, stream>>>(E, vT, out, nullptr, 1024, 1024, 256, 1024,
                                                   1048576, 262144, 262144);
}